// Round 5
// baseline (7654.166 us; speedup 1.0000x reference)
//
#include <hip/hip_runtime.h>
#include <hip/hip_bf16.h>

#define N_NODES 50000
#define N_EDGES 800000
#define MAX_ITER 20
#define PROP_GRID 2048

typedef __attribute__((ext_vector_type(8))) short bf16x8;
typedef __attribute__((ext_vector_type(4))) float f32x4;

__device__ __forceinline__ float gelu_f(float x){
  return 0.5f*x*(1.0f+erff(x*0.70710678118654752f));
}
__device__ __forceinline__ ushort f2b(float f){
  uint x = __float_as_uint(f);
  uint r = (x + 0x7fffu + ((x>>16)&1u)) >> 16;
  return (ushort)r;
}

// ---------------- setup: degree + counts ----------------
__global__ void deg_cnt_kernel(const int* __restrict__ col, const float* __restrict__ attr,
                               float* __restrict__ deg, int* __restrict__ cnt){
  int e = blockIdx.x*256 + threadIdx.x;
  if (e < N_EDGES){
    int c = col[e];
    atomicAdd(&deg[c], attr[e]);
    atomicAdd(&cnt[c], 1);
  }
}

__global__ void norm_kernel(const int* __restrict__ row, const int* __restrict__ col,
                            const float* __restrict__ attr, const float* __restrict__ deg,
                            float* __restrict__ nrm){
  int e = blockIdx.x*256 + threadIdx.x;
  if (e < N_EDGES){
    float dr = deg[row[e]], dc = deg[col[e]];
    float ir = dr > 0.f ? rsqrtf(dr) : 0.f;
    float ic = dc > 0.f ? rsqrtf(dc) : 0.f;
    nrm[e] = ir * attr[e] * ic;
  }
}

__global__ void scan_kernel(const int* __restrict__ cnt, int* __restrict__ starts,
                            int* __restrict__ cursor){
  __shared__ int buf[1024];
  __shared__ int carry;
  int tid = threadIdx.x;
  if (tid==0) carry = 0;
  __syncthreads();
  for (int base=0; base<N_NODES; base+=1024){
    int i = base+tid;
    int v = (i<N_NODES)? cnt[i] : 0;
    int cv = carry;
    buf[tid]=v;
    __syncthreads();
    for (int off=1; off<1024; off<<=1){
      int t = (tid>=off)? buf[tid-off] : 0;
      __syncthreads();
      buf[tid]+=t;
      __syncthreads();
    }
    int excl = buf[tid]-v+cv;
    if (i<N_NODES){ starts[i]=excl; cursor[i]=excl; }
    __syncthreads();
    if (tid==0) carry = cv + buf[1023];
    __syncthreads();
  }
  if (tid==0) starts[N_NODES] = carry;
}

// build interleaved (row, nrm) pairs in CSR order
__global__ void fill_kernel(const int* __restrict__ row, const int* __restrict__ col,
                            const float* __restrict__ nrm, int* __restrict__ cursor,
                            int2* __restrict__ ep){
  int e = blockIdx.x*256+threadIdx.x;
  if (e<N_EDGES){
    int c = col[e];
    int p = atomicAdd(&cursor[c],1);
    ep[p] = make_int2(row[e], __float_as_int(nrm[e]));
  }
}

// ---------------- weight packs (bf16 MFMA fragment layout) ----------------
__global__ void pack_w1(const float* __restrict__ W, ushort* __restrict__ PB){
  int i = blockIdx.x*256+threadIdx.x;
  if (i < 4*8*128*8){
    int e = i&7; int n = (i>>3)&127; int kb = (i>>10)&7; int j = i>>13;
    int k = kb*8+e;
    PB[i] = f2b(W[((size_t)j*67 + k)*128 + n]);
  }
}
__global__ void pack_w2(const float* __restrict__ W, ushort* __restrict__ PB){
  int i = blockIdx.x*256+threadIdx.x;
  if (i < 4*16*128*8){
    int e = i&7; int n = (i>>3)&127; int kb = (i>>10)&15; int j = i>>14;
    int k = kb*8+e;
    PB[i] = f2b(W[((size_t)j*128 + k)*128 + n]);
  }
}
__global__ void pack_w3(const float* __restrict__ W, ushort* __restrict__ PB){
  int i = blockIdx.x*256+threadIdx.x;
  if (i < 16*256*8){
    int e = i&7; int n = (i>>3)&255; int kb = i>>11;
    int k = kb*8+e;
    PB[i] = f2b(W[(((size_t)(n>>6))*128 + k)*64 + (n&63)]);
  }
}

// ---------------- up MLP -> z (bf16, stride 64) ----------------
__global__ __launch_bounds__(256) void mlp_up_kernel(
    const float* __restrict__ x, const float* __restrict__ w1, const float* __restrict__ b1,
    const float* __restrict__ w2, const float* __restrict__ b2, ushort* __restrict__ z){
  __shared__ float sw1[4*64];
  __shared__ float sw2[64*64];
  __shared__ float sb1[64], sb2[64];
  __shared__ float t1s[4][64];
  int tid = threadIdx.x;
  for (int i=tid;i<256;i+=256) sw1[i]=w1[i];
  for (int i=tid;i<4096;i+=256) sw2[i]=w2[i];
  if (tid<64){ sb1[tid]=b1[tid]; sb2[tid]=b2[tid]; }
  __syncthreads();
  int g = tid>>6;
  int c = tid&63;
  int node = blockIdx.x*4 + g;
  float acc = sb1[c];
  #pragma unroll
  for (int k=0;k<4;k++) acc += x[node*4+k]*sw1[k*64+c];
  t1s[g][c] = gelu_f(acc);
  __syncthreads();
  float acc2 = sb2[c];
  #pragma unroll 8
  for (int k=0;k<64;k++) acc2 += t1s[g][k]*sw2[k*64+c];
  z[(size_t)node*64+c] = f2b(acc2);
}

// ---------------- pos propagation (fp32, once) ----------------
template<int LDIN>
__global__ void posprop(const float* __restrict__ in, float* __restrict__ out,
                        const int* __restrict__ starts, const int2* __restrict__ ep){
  int v = blockIdx.x*256+threadIdx.x;
  if (v >= N_NODES) return;
  int s=starts[v], e=starts[v+1];
  float a0=0.f,a1=0.f,a2=0.f;
  for (int i=s;i<e;++i){
    int2 ed = ep[i];
    float nm = __int_as_float(ed.y);
    a0 = fmaf(in[(size_t)ed.x*LDIN+0], nm, a0);
    a1 = fmaf(in[(size_t)ed.x*LDIN+1], nm, a1);
    a2 = fmaf(in[(size_t)ed.x*LDIN+2], nm, a2);
  }
  float4 o = {a0,a1,a2,0.f};
  *(float4*)(out + (size_t)v*4) = o;
}

__global__ __launch_bounds__(256) void posbias_kernel(
    const float* __restrict__ pos, const float* __restrict__ P1,
    const float* __restrict__ P2, const float* __restrict__ P3,
    const float* __restrict__ c1w, const float* __restrict__ c1b,
    ushort* __restrict__ pb){
  __shared__ float sw[4][3][128];
  int tid=threadIdx.x;
  for (int i=tid; i<4*3*128; i+=256){
    int cc=i&127; int d=(i>>7)%3; int j=i/(3*128);
    sw[j][d][cc] = c1w[((size_t)j*67 + 64 + d)*128 + cc];
  }
  __syncthreads();
  int idx = blockIdx.x*256+tid;
  if (idx < N_NODES*128){
    int n = idx>>7, cc = idx&127;
    float a = c1b[cc];
    #pragma unroll
    for (int d=0;d<3;d++) a = fmaf(pos[(size_t)n*3+d], sw[0][d][cc], a);
    #pragma unroll
    for (int d=0;d<3;d++) a = fmaf(P1[(size_t)n*4+d], sw[1][d][cc], a);
    #pragma unroll
    for (int d=0;d<3;d++) a = fmaf(P2[(size_t)n*4+d], sw[2][d][cc], a);
    #pragma unroll
    for (int d=0;d<3;d++) a = fmaf(P3[(size_t)n*4+d], sw[3][d][cc], a);
    pb[idx]=f2b(a);
  }
}

// ---------------- prop 128ch: wave/node, 4-deep gather pipeline ----------------
__global__ __launch_bounds__(256) void prop128(
    const ushort* __restrict__ h, ushort* __restrict__ out,
    const int* __restrict__ starts, const int2* __restrict__ ep){
  int wv = threadIdx.x >> 6;
  int t = threadIdx.x & 63;
  int g = t >> 4;          // edge slot 0..3
  int c = t & 15;          // channel slot (8 ch each)
  const long long* epl = (const long long*)ep;
  for (int v = blockIdx.x*4 + wv; v < N_NODES; v += PROP_GRID*4){
    int s = starts[v], e = starts[v+1];
    float acc[8] = {0,0,0,0,0,0,0,0};
    for (int i=s; i<e; i+=16){
      int iA=i+g, iB=i+4+g, iC=i+8+g, iD=i+12+g;
      long long pA=0,pB=0,pC=0,pD=0;
      if (iA<e) pA = __builtin_nontemporal_load(epl+iA);
      if (iB<e) pB = __builtin_nontemporal_load(epl+iB);
      if (iC<e) pC = __builtin_nontemporal_load(epl+iC);
      if (iD<e) pD = __builtin_nontemporal_load(epl+iD);
      int  rA=(int)pA, rB=(int)pB, rC=(int)pC, rD=(int)pD;
      float wA=__int_as_float((int)(pA>>32)), wB=__int_as_float((int)(pB>>32));
      float wC=__int_as_float((int)(pC>>32)), wD=__int_as_float((int)(pD>>32));
      uint4 hA = *(const uint4*)(h + (size_t)rA*128 + c*8);
      uint4 hB = *(const uint4*)(h + (size_t)rB*128 + c*8);
      uint4 hC = *(const uint4*)(h + (size_t)rC*128 + c*8);
      uint4 hD = *(const uint4*)(h + (size_t)rD*128 + c*8);
      const uint* qA=(const uint*)&hA; const uint* qB=(const uint*)&hB;
      const uint* qC=(const uint*)&hC; const uint* qD=(const uint*)&hD;
      #pragma unroll
      for (int q=0;q<4;q++){
        acc[2*q]   = fmaf(__uint_as_float(qA[q]<<16),         wA, acc[2*q]);
        acc[2*q+1] = fmaf(__uint_as_float(qA[q]&0xffff0000u), wA, acc[2*q+1]);
        acc[2*q]   = fmaf(__uint_as_float(qB[q]<<16),         wB, acc[2*q]);
        acc[2*q+1] = fmaf(__uint_as_float(qB[q]&0xffff0000u), wB, acc[2*q+1]);
        acc[2*q]   = fmaf(__uint_as_float(qC[q]<<16),         wC, acc[2*q]);
        acc[2*q+1] = fmaf(__uint_as_float(qC[q]&0xffff0000u), wC, acc[2*q+1]);
        acc[2*q]   = fmaf(__uint_as_float(qD[q]<<16),         wD, acc[2*q]);
        acc[2*q+1] = fmaf(__uint_as_float(qD[q]&0xffff0000u), wD, acc[2*q+1]);
      }
    }
    #pragma unroll
    for (int q=0;q<8;q++){
      acc[q] += __shfl_xor(acc[q], 16, 64);
      acc[q] += __shfl_xor(acc[q], 32, 64);
    }
    if (g==0){
      uint4 o; uint* op=(uint*)&o;
      #pragma unroll
      for (int q=0;q<4;q++) op[q] = (uint)f2b(acc[2*q]) | ((uint)f2b(acc[2*q+1])<<16);
      *(uint4*)(out + (size_t)v*128 + c*8) = o;
    }
  }
}

// ---------------- prop 64ch: 4-deep gather pipeline ----------------
// MODE 0: write bf16; 1: +adj bf16; 2: +adj+bias logsoftmax bf16; 3: +adj+bias logsoftmax fp32
template<int MODE>
__global__ __launch_bounds__(256) void prop64(
    const ushort* __restrict__ h, void* __restrict__ outp,
    const ushort* __restrict__ adj, const float* __restrict__ bias,
    const int* __restrict__ starts, const int2* __restrict__ ep){
  int wv = threadIdx.x >> 6;
  int t = threadIdx.x & 63;
  int g = t >> 3;          // edge slot 0..7
  int c = t & 7;           // channel slot (8 ch each)
  const long long* epl = (const long long*)ep;
  for (int v = blockIdx.x*4 + wv; v < N_NODES; v += PROP_GRID*4){
    int s = starts[v], e = starts[v+1];
    float acc[8] = {0,0,0,0,0,0,0,0};
    for (int i=s; i<e; i+=32){
      int iA=i+g, iB=i+8+g, iC=i+16+g, iD=i+24+g;
      long long pA=0,pB=0,pC=0,pD=0;
      if (iA<e) pA = __builtin_nontemporal_load(epl+iA);
      if (iB<e) pB = __builtin_nontemporal_load(epl+iB);
      if (iC<e) pC = __builtin_nontemporal_load(epl+iC);
      if (iD<e) pD = __builtin_nontemporal_load(epl+iD);
      int  rA=(int)pA, rB=(int)pB, rC=(int)pC, rD=(int)pD;
      float wA=__int_as_float((int)(pA>>32)), wB=__int_as_float((int)(pB>>32));
      float wC=__int_as_float((int)(pC>>32)), wD=__int_as_float((int)(pD>>32));
      uint4 hA = *(const uint4*)(h + (size_t)rA*64 + c*8);
      uint4 hB = *(const uint4*)(h + (size_t)rB*64 + c*8);
      uint4 hC = *(const uint4*)(h + (size_t)rC*64 + c*8);
      uint4 hD = *(const uint4*)(h + (size_t)rD*64 + c*8);
      const uint* qA=(const uint*)&hA; const uint* qB=(const uint*)&hB;
      const uint* qC=(const uint*)&hC; const uint* qD=(const uint*)&hD;
      #pragma unroll
      for (int q=0;q<4;q++){
        acc[2*q]   = fmaf(__uint_as_float(qA[q]<<16),         wA, acc[2*q]);
        acc[2*q+1] = fmaf(__uint_as_float(qA[q]&0xffff0000u), wA, acc[2*q+1]);
        acc[2*q]   = fmaf(__uint_as_float(qB[q]<<16),         wB, acc[2*q]);
        acc[2*q+1] = fmaf(__uint_as_float(qB[q]&0xffff0000u), wB, acc[2*q+1]);
        acc[2*q]   = fmaf(__uint_as_float(qC[q]<<16),         wC, acc[2*q]);
        acc[2*q+1] = fmaf(__uint_as_float(qC[q]&0xffff0000u), wC, acc[2*q+1]);
        acc[2*q]   = fmaf(__uint_as_float(qD[q]<<16),         wD, acc[2*q]);
        acc[2*q+1] = fmaf(__uint_as_float(qD[q]&0xffff0000u), wD, acc[2*q+1]);
      }
    }
    #pragma unroll
    for (int q=0;q<8;q++){
      acc[q] += __shfl_xor(acc[q], 8, 64);
      acc[q] += __shfl_xor(acc[q], 16, 64);
      acc[q] += __shfl_xor(acc[q], 32, 64);
    }
    if (MODE==0){
      if (g==0){
        uint4 o; uint* op=(uint*)&o;
        #pragma unroll
        for (int q=0;q<4;q++) op[q] = (uint)f2b(acc[2*q]) | ((uint)f2b(acc[2*q+1])<<16);
        *(uint4*)((ushort*)outp + (size_t)v*64 + c*8) = o;
      }
    } else if (MODE==1){
      if (g==0){
        uint4 av = *(const uint4*)(adj + (size_t)v*64 + c*8);
        const uint* ap=(const uint*)&av;
        uint4 o; uint* op=(uint*)&o;
        #pragma unroll
        for (int q=0;q<4;q++){
          float lo = acc[2*q]   + __uint_as_float(ap[q]<<16);
          float hi = acc[2*q+1] + __uint_as_float(ap[q]&0xffff0000u);
          op[q] = (uint)f2b(lo) | ((uint)f2b(hi)<<16);
        }
        *(uint4*)((ushort*)outp + (size_t)v*64 + c*8) = o;
      }
    } else {
      uint4 av = *(const uint4*)(adj + (size_t)v*64 + c*8);
      const uint* ap=(const uint*)&av;
      float vv[8];
      #pragma unroll
      for (int q=0;q<4;q++){
        vv[2*q]   = acc[2*q]   + __uint_as_float(ap[q]<<16)         + bias[c*8+2*q];
        vv[2*q+1] = acc[2*q+1] + __uint_as_float(ap[q]&0xffff0000u) + bias[c*8+2*q+1];
      }
      float m = vv[0];
      #pragma unroll
      for (int q=1;q<8;q++) m = fmaxf(m, vv[q]);
      m = fmaxf(m, __shfl_xor(m,1,64));
      m = fmaxf(m, __shfl_xor(m,2,64));
      m = fmaxf(m, __shfl_xor(m,4,64));
      float ssum = 0.f;
      #pragma unroll
      for (int q=0;q<8;q++) ssum += __expf(vv[q]-m);
      ssum += __shfl_xor(ssum,1,64);
      ssum += __shfl_xor(ssum,2,64);
      ssum += __shfl_xor(ssum,4,64);
      float lse = m + __logf(ssum);
      if (g==0){
        if (MODE==2){
          uint4 o; uint* op=(uint*)&o;
          #pragma unroll
          for (int q=0;q<4;q++) op[q] = (uint)f2b(vv[2*q]-lse) | ((uint)f2b(vv[2*q+1]-lse)<<16);
          *(uint4*)((ushort*)outp + (size_t)v*64 + c*8) = o;
        } else {
          float* zo = (float*)outp + (size_t)v*64 + c*8;
          float4 o0 = {vv[0]-lse, vv[1]-lse, vv[2]-lse, vv[3]-lse};
          float4 o1 = {vv[4]-lse, vv[5]-lse, vv[6]-lse, vv[7]-lse};
          *(float4*)zo = o0;
          *(float4*)(zo+4) = o1;
        }
      }
    }
  }
}

// ---------------- MFMA gemm, 4 inputs (stride KC) -> 128 out, relu; M=32/wave ----------------
template<int KC, bool PERNODE_BIAS>
__global__ __launch_bounds__(256) void gemm4in(
    const ushort* __restrict__ H0, const ushort* __restrict__ H1,
    const ushort* __restrict__ H2, const ushort* __restrict__ H3,
    const ushort* __restrict__ PB, const void* __restrict__ biasp,
    ushort* __restrict__ out){
  constexpr int NT = 8;
  constexpr int NKS = KC/32;
  int lane = threadIdx.x & 63;
  int wv   = threadIdx.x >> 6;
  int m0 = blockIdx.x*128 + wv*32;
  int lr = lane & 15, lg = lane >> 4;
  int ar0 = min(m0 + lr,      N_NODES-1);
  int ar1 = min(m0 + 16 + lr, N_NODES-1);
  const ushort* Hs[4] = {H0,H1,H2,H3};
  f32x4 acc[2][NT];
  #pragma unroll
  for (int rt=0;rt<2;rt++)
    #pragma unroll
    for (int t=0;t<NT;t++) acc[rt][t] = (f32x4){0.f,0.f,0.f,0.f};
  #pragma unroll
  for (int j=0;j<4;j++){
    const ushort* Hj0 = Hs[j] + (size_t)ar0*KC + lg*8;
    const ushort* Hj1 = Hs[j] + (size_t)ar1*KC + lg*8;
    const ushort* PBj = PB + (size_t)j*(KC/8)*128*8;
    #pragma unroll
    for (int ks=0; ks<NKS; ks++){
      bf16x8 a0 = *(const bf16x8*)(Hj0 + ks*32);
      bf16x8 a1 = *(const bf16x8*)(Hj1 + ks*32);
      int kb = ks*4 + lg;
      #pragma unroll
      for (int t=0;t<NT;t++){
        bf16x8 bf = *(const bf16x8*)(PBj + ((size_t)kb*128 + t*16 + lr)*8);
        acc[0][t] = __builtin_amdgcn_mfma_f32_16x16x32_bf16(a0, bf, acc[0][t], 0, 0, 0);
        acc[1][t] = __builtin_amdgcn_mfma_f32_16x16x32_bf16(a1, bf, acc[1][t], 0, 0, 0);
      }
    }
  }
  #pragma unroll
  for (int rt=0;rt<2;rt++){
    #pragma unroll
    for (int t=0;t<NT;t++){
      #pragma unroll
      for (int q=0;q<4;q++){
        int node = m0 + rt*16 + lg*4 + q;
        if (node < N_NODES){
          int col = t*16 + lr;
          float b;
          if (PERNODE_BIAS) b = __uint_as_float(((uint)((const ushort*)biasp)[(size_t)node*128+col])<<16);
          else              b = ((const float*)biasp)[col];
          float vo = fmaxf(acc[rt][t][q] + b, 0.f);
          out[(size_t)node*128 + col] = f2b(vo);
        }
      }
    }
  }
}

// ---------------- MFMA gemm, 1 input (stride 128) -> 4x64 Y outputs; M=32/wave ----------------
__global__ __launch_bounds__(256) void gemm_y(
    const ushort* __restrict__ T2, const ushort* __restrict__ PB,
    ushort* __restrict__ Y){
  constexpr int NT = 16;
  int lane = threadIdx.x & 63;
  int wv   = threadIdx.x >> 6;
  int m0 = blockIdx.x*128 + wv*32;
  int lr = lane & 15, lg = lane >> 4;
  int ar0 = min(m0 + lr,      N_NODES-1);
  int ar1 = min(m0 + 16 + lr, N_NODES-1);
  f32x4 acc[2][NT];
  #pragma unroll
  for (int rt=0;rt<2;rt++)
    #pragma unroll
    for (int t=0;t<NT;t++) acc[rt][t] = (f32x4){0.f,0.f,0.f,0.f};
  const ushort* H0 = T2 + (size_t)ar0*128 + lg*8;
  const ushort* H1 = T2 + (size_t)ar1*128 + lg*8;
  #pragma unroll
  for (int ks=0; ks<4; ks++){
    bf16x8 a0 = *(const bf16x8*)(H0 + ks*32);
    bf16x8 a1 = *(const bf16x8*)(H1 + ks*32);
    int kb = ks*4 + lg;
    #pragma unroll
    for (int t=0;t<NT;t++){
      bf16x8 bf = *(const bf16x8*)(PB + ((size_t)kb*256 + t*16 + lr)*8);
      acc[0][t] = __builtin_amdgcn_mfma_f32_16x16x32_bf16(a0, bf, acc[0][t], 0, 0, 0);
      acc[1][t] = __builtin_amdgcn_mfma_f32_16x16x32_bf16(a1, bf, acc[1][t], 0, 0, 0);
    }
  }
  #pragma unroll
  for (int rt=0;rt<2;rt++){
    #pragma unroll
    for (int t=0;t<NT;t++){
      int n = t*16 + lr;
      int j = n >> 6, cc = n & 63;
      #pragma unroll
      for (int q=0;q<4;q++){
        int node = m0 + rt*16 + lg*4 + q;
        if (node < N_NODES)
          Y[(size_t)j*N_NODES*64 + (size_t)node*64 + cc] = f2b(acc[rt][t][q]);
      }
    }
  }
}

// ---------------- down MLP ----------------
__global__ __launch_bounds__(256) void mlp_down_kernel(
    const float* __restrict__ zs, const float* __restrict__ dw1, const float* __restrict__ db1,
    const float* __restrict__ dw2, const float* __restrict__ db2, float* __restrict__ out){
  int node = blockIdx.x*4 + (threadIdx.x>>6);
  int c = threadIdx.x & 63;
  float v = zs[(size_t)node*64+c]*dw1[c];
  #pragma unroll
  for (int off=32; off; off>>=1) v += __shfl_xor(v, off, 64);
  if (c==0) out[node] = gelu_f(v + db1[0]) * dw2[0] + db2[0];
}

extern "C" void kernel_launch(void* const* d_in, const int* in_sizes, int n_in,
                              void* d_out, int out_size, void* d_ws, size_t ws_size,
                              hipStream_t stream){
  const float* x     = (const float*)d_in[0];
  const float* pos   = (const float*)d_in[1];
  const float* eattr = (const float*)d_in[2];
  const float* up_w1 = (const float*)d_in[3];
  const float* up_b1 = (const float*)d_in[4];
  const float* up_w2 = (const float*)d_in[5];
  const float* up_b2 = (const float*)d_in[6];
  const float* c1_w  = (const float*)d_in[7];
  const float* c1_b  = (const float*)d_in[8];
  const float* c2_w  = (const float*)d_in[9];
  const float* c2_b  = (const float*)d_in[10];
  const float* c3_w  = (const float*)d_in[11];
  const float* c3_b  = (const float*)d_in[12];
  const float* dw1   = (const float*)d_in[13];
  const float* db1   = (const float*)d_in[14];
  const float* dw2   = (const float*)d_in[15];
  const float* db2   = (const float*)d_in[16];
  const int*   eidx  = (const int*)d_in[17];
  const int* row = eidx;
  const int* col = eidx + N_EDGES;

  char* wsp = (char*)d_ws;
  size_t off = 0;
  auto alloc = [&](size_t bytes)->char*{
    char* p = wsp + off;
    off = (off + bytes + 255) & ~(size_t)255;
    return p;
  };
  float*  deg    = (float*)alloc((size_t)N_NODES*4);
  int*    cnt    = (int*)  alloc((size_t)N_NODES*4);
  int*    starts = (int*)  alloc((size_t)(N_NODES+1)*4);
  int*    cursor = (int*)  alloc((size_t)N_NODES*4);
  float*  nrm    = (float*)alloc((size_t)N_EDGES*4);
  int2*   ep     = (int2*) alloc((size_t)N_EDGES*8);
  float*  P1     = (float*)alloc((size_t)N_NODES*4*4);
  float*  P2     = (float*)alloc((size_t)N_NODES*4*4);
  float*  P3     = (float*)alloc((size_t)N_NODES*4*4);
  ushort* pbias  = (ushort*)alloc((size_t)N_NODES*128*2);
  ushort* z      = (ushort*)alloc((size_t)N_NODES*64*2);
  ushort* q1     = (ushort*)alloc((size_t)N_NODES*64*2);
  ushort* q2     = (ushort*)alloc((size_t)N_NODES*64*2);
  ushort* q3     = (ushort*)alloc((size_t)N_NODES*64*2);
  ushort* t1     = (ushort*)alloc((size_t)N_NODES*128*2);
  ushort* p1     = (ushort*)alloc((size_t)N_NODES*128*2);
  ushort* p2     = (ushort*)alloc((size_t)N_NODES*128*2);
  ushort* p3     = (ushort*)alloc((size_t)N_NODES*128*2);
  ushort* t2     = (ushort*)alloc((size_t)N_NODES*128*2);
  ushort* PB1    = (ushort*)alloc((size_t)4*8*128*8*2);
  ushort* PB2    = (ushort*)alloc((size_t)4*16*128*8*2);
  ushort* PB3    = (ushort*)alloc((size_t)16*256*8*2);

  // aliases: Y overlays p1+p2 (dead by gemm_y); u1,u2 reuse q1,q2
  ushort* Y  = p1;
  ushort* Y0 = Y;
  ushort* Y1 = Y + (size_t)1*N_NODES*64;
  ushort* Y2 = Y + (size_t)2*N_NODES*64;
  ushort* Y3 = Y + (size_t)3*N_NODES*64;
  ushort* u1 = q1;
  ushort* u2 = q2;

  float* outv  = (float*)d_out;            // (N,1)
  float* zstar = (float*)d_out + N_NODES;  // (N,64)

  hipMemsetAsync(deg, 0, (size_t)N_NODES*4, stream);
  hipMemsetAsync(cnt, 0, (size_t)N_NODES*4, stream);
  int eb = (N_EDGES+255)/256;
  deg_cnt_kernel<<<eb,256,0,stream>>>(col, eattr, deg, cnt);
  norm_kernel<<<eb,256,0,stream>>>(row, col, eattr, deg, nrm);
  scan_kernel<<<1,1024,0,stream>>>(cnt, starts, cursor);
  fill_kernel<<<eb,256,0,stream>>>(row, col, nrm, cursor, ep);
  pack_w1<<<128,256,0,stream>>>(c1_w, PB1);
  pack_w2<<<256,256,0,stream>>>(c2_w, PB2);
  pack_w3<<<128,256,0,stream>>>(c3_w, PB3);
  mlp_up_kernel<<<N_NODES/4,256,0,stream>>>(x, up_w1, up_b1, up_w2, up_b2, z);

  int nb = (N_NODES+255)/256;
  posprop<3><<<nb,256,0,stream>>>(pos, P1, starts, ep);
  posprop<4><<<nb,256,0,stream>>>(P1,  P2, starts, ep);
  posprop<4><<<nb,256,0,stream>>>(P2,  P3, starts, ep);
  posbias_kernel<<<(N_NODES*128)/256,256,0,stream>>>(pos, P1, P2, P3, c1_w, c1_b, pbias);

  const int ggemm = (N_NODES+127)/128;     // 391 blocks (M=32/wave, 4 waves)

  for (int it=0; it<=MAX_ITER; ++it){
    // layer 1: propagate z (64ch), gemm K=64 with per-node posbias
    prop64<0><<<PROP_GRID,256,0,stream>>>(z,  q1, nullptr, nullptr, starts, ep);
    prop64<0><<<PROP_GRID,256,0,stream>>>(q1, q2, nullptr, nullptr, starts, ep);
    prop64<0><<<PROP_GRID,256,0,stream>>>(q2, q3, nullptr, nullptr, starts, ep);
    gemm4in<64,true><<<ggemm,256,0,stream>>>(z,q1,q2,q3,PB1,pbias,t1);

    // layer 2: direct TAG at 128ch
    prop128<<<PROP_GRID,256,0,stream>>>(t1,p1,starts,ep);
    prop128<<<PROP_GRID,256,0,stream>>>(p1,p2,starts,ep);
    prop128<<<PROP_GRID,256,0,stream>>>(p2,p3,starts,ep);
    gemm4in<128,false><<<ggemm,256,0,stream>>>(t1,p1,p2,p3,PB2,c2_b,t2);

    // layer 3: Horner — project first (128->4x64), then 64ch props
    gemm_y<<<ggemm,256,0,stream>>>(t2, PB3, Y);
    prop64<1><<<PROP_GRID,256,0,stream>>>(Y3, u1, Y2, nullptr, starts, ep);
    prop64<1><<<PROP_GRID,256,0,stream>>>(u1, u2, Y1, nullptr, starts, ep);
    if (it < MAX_ITER){
      prop64<2><<<PROP_GRID,256,0,stream>>>(u2, z, Y0, c3_b, starts, ep);
    } else {
      prop64<3><<<PROP_GRID,256,0,stream>>>(u2, zstar, Y0, c3_b, starts, ep);
    }
  }
  mlp_down_kernel<<<N_NODES/4,256,0,stream>>>(zstar, dw1, db1, dw2, db2, outv);
}

// Round 6
// 6940.418 us; speedup vs baseline: 1.1028x; 1.1028x over previous
//
#include <hip/hip_runtime.h>
#include <hip/hip_bf16.h>

#define N_NODES 50000
#define N_EDGES 800000
#define MAX_ITER 20

typedef __attribute__((ext_vector_type(8))) short bf16x8;
typedef __attribute__((ext_vector_type(4))) float f32x4;
typedef __attribute__((ext_vector_type(2))) float f32x2;
typedef unsigned char uchar;

__device__ __forceinline__ float gelu_f(float x){
  return 0.5f*x*(1.0f+erff(x*0.70710678118654752f));
}
__device__ __forceinline__ ushort f2b(float f){
  uint x = __float_as_uint(f);
  uint r = (x + 0x7fffu + ((x>>16)&1u)) >> 16;
  return (ushort)r;
}

// ---------------- fp8 e4m3 helpers (HW cvt on gfx950, sw fallback) ----------------
#if __has_builtin(__builtin_amdgcn_cvt_pk_f32_fp8) && __has_builtin(__builtin_amdgcn_cvt_pk_fp8_f32)
#define HW_FP8 1
#endif

__device__ __forceinline__ uint fp8_enc1_sw(float x){
  uint u = __float_as_uint(x);
  uint s = (u>>24)&0x80u;
  int e = (int)((u>>23)&0xffu);
  uint m = u&0x7fffffu;
  uint m3 = (m + 0x80000u)>>20;
  if (m3==8u){ e+=1; m3=0u; }
  int e8 = e-120;
  if (e8<=0) return s;
  if (e8>=15) return s|0x7eu;
  return s | ((uint)e8<<3) | m3;
}
__device__ __forceinline__ float fp8_dec1_sw(uint b){
  uint s=(b&0x80u)<<24;
  uint em=b&0x7fu;
  if (em==0u) return __uint_as_float(s);
  if ((em>>3)==0u) return (s?-1.f:1.f)*(float)em*0.001953125f;
  return __uint_as_float(s | ((em+960u)<<20));
}
__device__ __forceinline__ void fp8_dec8(uint lo, uint hi, float* d){
#ifdef HW_FP8
  f32x2 a = __builtin_amdgcn_cvt_pk_f32_fp8(lo,false);
  f32x2 b = __builtin_amdgcn_cvt_pk_f32_fp8(lo,true);
  f32x2 c = __builtin_amdgcn_cvt_pk_f32_fp8(hi,false);
  f32x2 e = __builtin_amdgcn_cvt_pk_f32_fp8(hi,true);
  d[0]=a[0];d[1]=a[1];d[2]=b[0];d[3]=b[1];d[4]=c[0];d[5]=c[1];d[6]=e[0];d[7]=e[1];
#else
  d[0]=fp8_dec1_sw(lo&0xffu);        d[1]=fp8_dec1_sw((lo>>8)&0xffu);
  d[2]=fp8_dec1_sw((lo>>16)&0xffu);  d[3]=fp8_dec1_sw(lo>>24);
  d[4]=fp8_dec1_sw(hi&0xffu);        d[5]=fp8_dec1_sw((hi>>8)&0xffu);
  d[6]=fp8_dec1_sw((hi>>16)&0xffu);  d[7]=fp8_dec1_sw(hi>>24);
#endif
}
__device__ __forceinline__ uint fp8_enc4(float a,float b,float c,float d){
#ifdef HW_FP8
  uint u = __builtin_amdgcn_cvt_pk_fp8_f32(a,b,0u,false);
  u = __builtin_amdgcn_cvt_pk_fp8_f32(c,d,u,true);
  return u;
#else
  return fp8_enc1_sw(a) | (fp8_enc1_sw(b)<<8) | (fp8_enc1_sw(c)<<16) | (fp8_enc1_sw(d)<<24);
#endif
}
__device__ __forceinline__ uchar fp8_enc1(float a){
#ifdef HW_FP8
  return (uchar)(__builtin_amdgcn_cvt_pk_fp8_f32(a,a,0u,false)&0xffu);
#else
  return (uchar)fp8_enc1_sw(a);
#endif
}

// ---------------- setup: degree + counts ----------------
__global__ void deg_cnt_kernel(const int* __restrict__ col, const float* __restrict__ attr,
                               float* __restrict__ deg, int* __restrict__ cnt){
  int e = blockIdx.x*256 + threadIdx.x;
  if (e < N_EDGES){
    int c = col[e];
    atomicAdd(&deg[c], attr[e]);
    atomicAdd(&cnt[c], 1);
  }
}

__global__ void norm_kernel(const int* __restrict__ row, const int* __restrict__ col,
                            const float* __restrict__ attr, const float* __restrict__ deg,
                            float* __restrict__ nrm){
  int e = blockIdx.x*256 + threadIdx.x;
  if (e < N_EDGES){
    float dr = deg[row[e]], dc = deg[col[e]];
    float ir = dr > 0.f ? rsqrtf(dr) : 0.f;
    float ic = dc > 0.f ? rsqrtf(dc) : 0.f;
    nrm[e] = ir * attr[e] * ic;
  }
}

__global__ void scan_kernel(const int* __restrict__ cnt, int* __restrict__ starts,
                            int* __restrict__ cursor){
  __shared__ int buf[1024];
  __shared__ int carry;
  int tid = threadIdx.x;
  if (tid==0) carry = 0;
  __syncthreads();
  for (int base=0; base<N_NODES; base+=1024){
    int i = base+tid;
    int v = (i<N_NODES)? cnt[i] : 0;
    int cv = carry;
    buf[tid]=v;
    __syncthreads();
    for (int off=1; off<1024; off<<=1){
      int t = (tid>=off)? buf[tid-off] : 0;
      __syncthreads();
      buf[tid]+=t;
      __syncthreads();
    }
    int excl = buf[tid]-v+cv;
    if (i<N_NODES){ starts[i]=excl; cursor[i]=excl; }
    __syncthreads();
    if (tid==0) carry = cv + buf[1023];
    __syncthreads();
  }
  if (tid==0) starts[N_NODES] = carry;
}

__global__ void fill_kernel(const int* __restrict__ row, const int* __restrict__ col,
                            const float* __restrict__ nrm, int* __restrict__ cursor,
                            int* __restrict__ csr_row, float* __restrict__ csr_nrm){
  int e = blockIdx.x*256+threadIdx.x;
  if (e<N_EDGES){
    int c = col[e];
    int p = atomicAdd(&cursor[c],1);
    csr_row[p]=row[e];
    csr_nrm[p]=nrm[e];
  }
}

// ---------------- weight packs (bf16 MFMA fragment layout) ----------------
__global__ void pack_w1(const float* __restrict__ W, ushort* __restrict__ PB){
  int i = blockIdx.x*256+threadIdx.x;
  if (i < 4*8*128*8){
    int e = i&7; int n = (i>>3)&127; int kb = (i>>10)&7; int j = i>>13;
    int k = kb*8+e;
    PB[i] = f2b(W[((size_t)j*67 + k)*128 + n]);
  }
}
__global__ void pack_w2(const float* __restrict__ W, ushort* __restrict__ PB){
  int i = blockIdx.x*256+threadIdx.x;
  if (i < 4*16*128*8){
    int e = i&7; int n = (i>>3)&127; int kb = (i>>10)&15; int j = i>>14;
    int k = kb*8+e;
    PB[i] = f2b(W[((size_t)j*128 + k)*128 + n]);
  }
}
__global__ void pack_w3(const float* __restrict__ W, ushort* __restrict__ PB){
  int i = blockIdx.x*256+threadIdx.x;
  if (i < 16*256*8){
    int e = i&7; int n = (i>>3)&255; int kb = i>>11;
    int k = kb*8+e;
    PB[i] = f2b(W[(((size_t)(n>>6))*128 + k)*64 + (n&63)]);
  }
}

// ---------------- up MLP -> z bf16 + z8 fp8 ----------------
__global__ __launch_bounds__(256) void mlp_up_kernel(
    const float* __restrict__ x, const float* __restrict__ w1, const float* __restrict__ b1,
    const float* __restrict__ w2, const float* __restrict__ b2,
    ushort* __restrict__ z, uchar* __restrict__ z8){
  __shared__ float sw1[4*64];
  __shared__ float sw2[64*64];
  __shared__ float sb1[64], sb2[64];
  __shared__ float t1s[4][64];
  int tid = threadIdx.x;
  for (int i=tid;i<256;i+=256) sw1[i]=w1[i];
  for (int i=tid;i<4096;i+=256) sw2[i]=w2[i];
  if (tid<64){ sb1[tid]=b1[tid]; sb2[tid]=b2[tid]; }
  __syncthreads();
  int g = tid>>6;
  int c = tid&63;
  int node = blockIdx.x*4 + g;
  float acc = sb1[c];
  #pragma unroll
  for (int k=0;k<4;k++) acc += x[node*4+k]*sw1[k*64+c];
  t1s[g][c] = gelu_f(acc);
  __syncthreads();
  float acc2 = sb2[c];
  #pragma unroll 8
  for (int k=0;k<64;k++) acc2 += t1s[g][k]*sw2[k*64+c];
  z[(size_t)node*64+c] = f2b(acc2);
  z8[(size_t)node*64+c] = fp8_enc1(acc2);
}

// ---------------- pos propagation (fp32, once) ----------------
template<int LDIN>
__global__ void posprop(const float* __restrict__ in, float* __restrict__ out,
                        const int* __restrict__ starts, const int* __restrict__ crow,
                        const float* __restrict__ cnrm){
  int v = blockIdx.x*256+threadIdx.x;
  if (v >= N_NODES) return;
  int s=starts[v], e=starts[v+1];
  float a0=0.f,a1=0.f,a2=0.f;
  for (int i=s;i<e;++i){
    int r=crow[i]; float nm=cnrm[i];
    a0 = fmaf(in[(size_t)r*LDIN+0], nm, a0);
    a1 = fmaf(in[(size_t)r*LDIN+1], nm, a1);
    a2 = fmaf(in[(size_t)r*LDIN+2], nm, a2);
  }
  float4 o = {a0,a1,a2,0.f};
  *(float4*)(out + (size_t)v*4) = o;
}

__global__ __launch_bounds__(256) void posbias_kernel(
    const float* __restrict__ pos, const float* __restrict__ P1,
    const float* __restrict__ P2, const float* __restrict__ P3,
    const float* __restrict__ c1w, const float* __restrict__ c1b,
    ushort* __restrict__ pb){
  __shared__ float sw[4][3][128];
  int tid=threadIdx.x;
  for (int i=tid; i<4*3*128; i+=256){
    int cc=i&127; int d=(i>>7)%3; int j=i/(3*128);
    sw[j][d][cc] = c1w[((size_t)j*67 + 64 + d)*128 + cc];
  }
  __syncthreads();
  int idx = blockIdx.x*256+tid;
  if (idx < N_NODES*128){
    int n = idx>>7, cc = idx&127;
    float a = c1b[cc];
    #pragma unroll
    for (int d=0;d<3;d++) a = fmaf(pos[(size_t)n*3+d], sw[0][d][cc], a);
    #pragma unroll
    for (int d=0;d<3;d++) a = fmaf(P1[(size_t)n*4+d], sw[1][d][cc], a);
    #pragma unroll
    for (int d=0;d<3;d++) a = fmaf(P2[(size_t)n*4+d], sw[2][d][cc], a);
    #pragma unroll
    for (int d=0;d<3;d++) a = fmaf(P3[(size_t)n*4+d], sw[3][d][cc], a);
    pb[idx]=f2b(a);
  }
}

// ---------------- prop 64ch (R3 structure; IN8/OUT8 dtype variants) ----------------
// MODE 0: plain; 1: +adj; 2: +adj+bias logsoftmax -> bf16(+fp8); 3: +adj+bias logsoftmax -> fp32
template<int MODE, bool IN8, bool OUT8>
__global__ __launch_bounds__(256) void prop64k(
    const void* __restrict__ hin, ushort* __restrict__ obf,
    uchar* __restrict__ of8, float* __restrict__ of32,
    const ushort* __restrict__ adj, const float* __restrict__ bias,
    const int* __restrict__ starts, const int* __restrict__ crow,
    const float* __restrict__ cnrm){
  constexpr bool WBF = (MODE==0) || (MODE==2) || (MODE==1 && !OUT8);
  int wv = threadIdx.x >> 6;
  int v = blockIdx.x*4 + wv;
  int t = threadIdx.x & 63;
  int g = t >> 3;          // edge slot 0..7
  int c = t & 7;           // channel slot (8 ch each)
  int s = starts[v], e = starts[v+1];
  float acc[8] = {0,0,0,0,0,0,0,0};
  for (int i=s; i<e; i+=64){
    int cnt = e - i; if (cnt > 64) cnt = 64;
    int r = 0; float nm = 0.f;
    if (t < cnt){ r = crow[i+t]; nm = cnrm[i+t]; }
    for (int jb=0; jb<cnt; jb+=8){
      int rr = __shfl(r, jb+g, 64);
      float nmj = __shfl(nm, jb+g, 64);
      float hv[8];
      if (IN8){
        uint2 d = *(const uint2*)((const uchar*)hin + (size_t)rr*64 + c*8);
        fp8_dec8(d.x, d.y, hv);
      } else {
        uint4 d = *(const uint4*)((const ushort*)hin + (size_t)rr*64 + c*8);
        const uint* dp = (const uint*)&d;
        #pragma unroll
        for (int q=0;q<4;q++){
          hv[2*q]   = __uint_as_float(dp[q]<<16);
          hv[2*q+1] = __uint_as_float(dp[q]&0xffff0000u);
        }
      }
      #pragma unroll
      for (int q=0;q<8;q++) acc[q] = fmaf(hv[q], nmj, acc[q]);
    }
  }
  #pragma unroll
  for (int q=0;q<8;q++){
    acc[q] += __shfl_xor(acc[q], 8, 64);
    acc[q] += __shfl_xor(acc[q], 16, 64);
    acc[q] += __shfl_xor(acc[q], 32, 64);
  }
  if (MODE==0 || MODE==1){
    if (g==0){
      float val[8];
      if (MODE==1){
        uint4 av = *(const uint4*)(adj + (size_t)v*64 + c*8);
        const uint* ap=(const uint*)&av;
        #pragma unroll
        for (int q=0;q<4;q++){
          val[2*q]   = acc[2*q]   + __uint_as_float(ap[q]<<16);
          val[2*q+1] = acc[2*q+1] + __uint_as_float(ap[q]&0xffff0000u);
        }
      } else {
        #pragma unroll
        for (int q=0;q<8;q++) val[q]=acc[q];
      }
      if (WBF){
        uint4 o; uint* op=(uint*)&o;
        #pragma unroll
        for (int q=0;q<4;q++) op[q] = (uint)f2b(val[2*q]) | ((uint)f2b(val[2*q+1])<<16);
        *(uint4*)(obf + (size_t)v*64 + c*8) = o;
      }
      if (OUT8){
        uint2 o8;
        o8.x = fp8_enc4(val[0],val[1],val[2],val[3]);
        o8.y = fp8_enc4(val[4],val[5],val[6],val[7]);
        *(uint2*)(of8 + (size_t)v*64 + c*8) = o8;
      }
    }
  } else {
    uint4 av = *(const uint4*)(adj + (size_t)v*64 + c*8);
    const uint* ap=(const uint*)&av;
    float vv[8];
    #pragma unroll
    for (int q=0;q<4;q++){
      vv[2*q]   = acc[2*q]   + __uint_as_float(ap[q]<<16)         + bias[c*8+2*q];
      vv[2*q+1] = acc[2*q+1] + __uint_as_float(ap[q]&0xffff0000u) + bias[c*8+2*q+1];
    }
    float m = vv[0];
    #pragma unroll
    for (int q=1;q<8;q++) m = fmaxf(m, vv[q]);
    m = fmaxf(m, __shfl_xor(m,1,64));
    m = fmaxf(m, __shfl_xor(m,2,64));
    m = fmaxf(m, __shfl_xor(m,4,64));
    float ss = 0.f;
    #pragma unroll
    for (int q=0;q<8;q++) ss += __expf(vv[q]-m);
    ss += __shfl_xor(ss,1,64);
    ss += __shfl_xor(ss,2,64);
    ss += __shfl_xor(ss,4,64);
    float lse = m + __logf(ss);
    if (g==0){
      if (MODE==2){
        uint4 o; uint* op=(uint*)&o;
        #pragma unroll
        for (int q=0;q<4;q++) op[q] = (uint)f2b(vv[2*q]-lse) | ((uint)f2b(vv[2*q+1]-lse)<<16);
        *(uint4*)(obf + (size_t)v*64 + c*8) = o;
        if (OUT8){
          uint2 o8;
          o8.x = fp8_enc4(vv[0]-lse,vv[1]-lse,vv[2]-lse,vv[3]-lse);
          o8.y = fp8_enc4(vv[4]-lse,vv[5]-lse,vv[6]-lse,vv[7]-lse);
          *(uint2*)(of8 + (size_t)v*64 + c*8) = o8;
        }
      } else {
        float* zo = of32 + (size_t)v*64 + c*8;
        float4 o0 = {vv[0]-lse, vv[1]-lse, vv[2]-lse, vv[3]-lse};
        float4 o1 = {vv[4]-lse, vv[5]-lse, vv[6]-lse, vv[7]-lse};
        *(float4*)zo = o0;
        *(float4*)(zo+4) = o1;
      }
    }
  }
}

// ---------------- prop 128ch (R3 structure; IN8/OUT8 variants) ----------------
template<bool IN8, bool OUT8>
__global__ __launch_bounds__(256) void prop128k(
    const void* __restrict__ hin, ushort* __restrict__ obf,
    uchar* __restrict__ of8,
    const int* __restrict__ starts, const int* __restrict__ crow,
    const float* __restrict__ cnrm){
  int wv = threadIdx.x >> 6;
  int v = blockIdx.x*4 + wv;
  int t = threadIdx.x & 63;
  int g = t >> 4;          // edge slot 0..3
  int c = t & 15;          // channel slot (8 ch each)
  int s = starts[v], e = starts[v+1];
  float acc[8] = {0,0,0,0,0,0,0,0};
  for (int i=s; i<e; i+=64){
    int cnt = e - i; if (cnt > 64) cnt = 64;
    int r = 0; float nm = 0.f;
    if (t < cnt){ r = crow[i+t]; nm = cnrm[i+t]; }
    for (int jb=0; jb<cnt; jb+=4){
      int rr  = __shfl(r,  jb+g, 64);
      float nmj = __shfl(nm, jb+g, 64);
      float hv[8];
      if (IN8){
        uint2 d = *(const uint2*)((const uchar*)hin + (size_t)rr*128 + c*8);
        fp8_dec8(d.x, d.y, hv);
      } else {
        uint4 d = *(const uint4*)((const ushort*)hin + (size_t)rr*128 + c*8);
        const uint* dp = (const uint*)&d;
        #pragma unroll
        for (int q=0;q<4;q++){
          hv[2*q]   = __uint_as_float(dp[q]<<16);
          hv[2*q+1] = __uint_as_float(dp[q]&0xffff0000u);
        }
      }
      #pragma unroll
      for (int q=0;q<8;q++) acc[q] = fmaf(hv[q], nmj, acc[q]);
    }
  }
  #pragma unroll
  for (int q=0;q<8;q++){
    acc[q] += __shfl_xor(acc[q], 16, 64);
    acc[q] += __shfl_xor(acc[q], 32, 64);
  }
  if (g==0){
    uint4 o; uint* op=(uint*)&o;
    #pragma unroll
    for (int q=0;q<4;q++) op[q] = (uint)f2b(acc[2*q]) | ((uint)f2b(acc[2*q+1])<<16);
    *(uint4*)(obf + (size_t)v*128 + c*8) = o;
    if (OUT8){
      uint2 o8;
      o8.x = fp8_enc4(acc[0],acc[1],acc[2],acc[3]);
      o8.y = fp8_enc4(acc[4],acc[5],acc[6],acc[7]);
      *(uint2*)(of8 + (size_t)v*128 + c*8) = o8;
    }
  }
}

// ---------------- MFMA gemm, 4 inputs (stride KC) -> 128 out, relu ----------------
template<int KC, bool PERNODE_BIAS, bool OUT8>
__global__ __launch_bounds__(256) void gemm4in(
    const ushort* __restrict__ H0, const ushort* __restrict__ H1,
    const ushort* __restrict__ H2, const ushort* __restrict__ H3,
    const ushort* __restrict__ PB, const void* __restrict__ biasp,
    ushort* __restrict__ out, uchar* __restrict__ out8){
  constexpr int NT = 8;
  constexpr int NKS = KC/32;
  int lane = threadIdx.x & 63;
  int wv   = threadIdx.x >> 6;
  int m0 = blockIdx.x*64 + wv*16;
  int lr = lane & 15, lg = lane >> 4;
  int arow = m0 + lr; if (arow > N_NODES-1) arow = N_NODES-1;
  const ushort* Hs[4] = {H0,H1,H2,H3};
  f32x4 acc[NT];
  #pragma unroll
  for (int t=0;t<NT;t++) acc[t] = (f32x4){0.f,0.f,0.f,0.f};
  #pragma unroll
  for (int j=0;j<4;j++){
    const ushort* Hj  = Hs[j] + (size_t)arow*KC + lg*8;
    const ushort* PBj = PB + (size_t)j*(KC/8)*128*8;
    #pragma unroll
    for (int ks=0; ks<NKS; ks++){
      bf16x8 af = *(const bf16x8*)(Hj + ks*32);
      int kb = ks*4 + lg;
      #pragma unroll
      for (int t=0;t<NT;t++){
        bf16x8 bf = *(const bf16x8*)(PBj + ((size_t)kb*128 + t*16 + lr)*8);
        acc[t] = __builtin_amdgcn_mfma_f32_16x16x32_bf16(af, bf, acc[t], 0, 0, 0);
      }
    }
  }
  #pragma unroll
  for (int t=0;t<NT;t++){
    #pragma unroll
    for (int q=0;q<4;q++){
      int node = m0 + lg*4 + q;
      if (node < N_NODES){
        int col = t*16 + lr;
        float b;
        if (PERNODE_BIAS) b = __uint_as_float(((uint)((const ushort*)biasp)[(size_t)node*128+col])<<16);
        else              b = ((const float*)biasp)[col];
        float vo = fmaxf(acc[t][q] + b, 0.f);
        out[(size_t)node*128 + col] = f2b(vo);
        if (OUT8) out8[(size_t)node*128 + col] = fp8_enc1(vo);
      }
    }
  }
}

// ---------------- MFMA gemm, 1 input (stride 128) -> 4x64 Y outputs (+Y3 fp8) ----------------
__global__ __launch_bounds__(256) void gemm_y(
    const ushort* __restrict__ T2, const ushort* __restrict__ PB,
    ushort* __restrict__ Y, uchar* __restrict__ Y3_8){
  constexpr int NT = 16;
  int lane = threadIdx.x & 63;
  int wv   = threadIdx.x >> 6;
  int m0 = blockIdx.x*64 + wv*16;
  int lr = lane & 15, lg = lane >> 4;
  int arow = m0 + lr; if (arow > N_NODES-1) arow = N_NODES-1;
  f32x4 acc[NT];
  #pragma unroll
  for (int t=0;t<NT;t++) acc[t] = (f32x4){0.f,0.f,0.f,0.f};
  const ushort* Hj = T2 + (size_t)arow*128 + lg*8;
  #pragma unroll
  for (int ks=0; ks<4; ks++){
    bf16x8 af = *(const bf16x8*)(Hj + ks*32);
    int kb = ks*4 + lg;
    #pragma unroll
    for (int t=0;t<NT;t++){
      bf16x8 bf = *(const bf16x8*)(PB + ((size_t)kb*256 + t*16 + lr)*8);
      acc[t] = __builtin_amdgcn_mfma_f32_16x16x32_bf16(af, bf, acc[t], 0, 0, 0);
    }
  }
  #pragma unroll
  for (int t=0;t<NT;t++){
    int n = t*16 + lr;
    int j = n >> 6, cc = n & 63;
    #pragma unroll
    for (int q=0;q<4;q++){
      int node = m0 + lg*4 + q;
      if (node < N_NODES){
        Y[(size_t)j*N_NODES*64 + (size_t)node*64 + cc] = f2b(acc[t][q]);
        if (j==3) Y3_8[(size_t)node*64 + cc] = fp8_enc1(acc[t][q]);
      }
    }
  }
}

// ---------------- down MLP ----------------
__global__ __launch_bounds__(256) void mlp_down_kernel(
    const float* __restrict__ zs, const float* __restrict__ dw1, const float* __restrict__ db1,
    const float* __restrict__ dw2, const float* __restrict__ db2, float* __restrict__ out){
  int node = blockIdx.x*4 + (threadIdx.x>>6);
  int c = threadIdx.x & 63;
  float v = zs[(size_t)node*64+c]*dw1[c];
  #pragma unroll
  for (int off=32; off; off>>=1) v += __shfl_xor(v, off, 64);
  if (c==0) out[node] = gelu_f(v + db1[0]) * dw2[0] + db2[0];
}

extern "C" void kernel_launch(void* const* d_in, const int* in_sizes, int n_in,
                              void* d_out, int out_size, void* d_ws, size_t ws_size,
                              hipStream_t stream){
  const float* x     = (const float*)d_in[0];
  const float* pos   = (const float*)d_in[1];
  const float* eattr = (const float*)d_in[2];
  const float* up_w1 = (const float*)d_in[3];
  const float* up_b1 = (const float*)d_in[4];
  const float* up_w2 = (const float*)d_in[5];
  const float* up_b2 = (const float*)d_in[6];
  const float* c1_w  = (const float*)d_in[7];
  const float* c1_b  = (const float*)d_in[8];
  const float* c2_w  = (const float*)d_in[9];
  const float* c2_b  = (const float*)d_in[10];
  const float* c3_w  = (const float*)d_in[11];
  const float* c3_b  = (const float*)d_in[12];
  const float* dw1   = (const float*)d_in[13];
  const float* db1   = (const float*)d_in[14];
  const float* dw2   = (const float*)d_in[15];
  const float* db2   = (const float*)d_in[16];
  const int*   eidx  = (const int*)d_in[17];
  const int* row = eidx;
  const int* col = eidx + N_EDGES;

  char* wsp = (char*)d_ws;
  size_t off = 0;
  auto alloc = [&](size_t bytes)->char*{
    char* p = wsp + off;
    off = (off + bytes + 255) & ~(size_t)255;
    return p;
  };
  float*  deg    = (float*)alloc((size_t)N_NODES*4);
  int*    cnt    = (int*)  alloc((size_t)N_NODES*4);
  int*    starts = (int*)  alloc((size_t)(N_NODES+1)*4);
  int*    cursor = (int*)  alloc((size_t)N_NODES*4);
  float*  nrm    = (float*)alloc((size_t)N_EDGES*4);
  int*    crow   = (int*)  alloc((size_t)N_EDGES*4);
  float*  cnrm   = (float*)alloc((size_t)N_EDGES*4);
  float*  P1     = (float*)alloc((size_t)N_NODES*4*4);
  float*  P2     = (float*)alloc((size_t)N_NODES*4*4);
  float*  P3     = (float*)alloc((size_t)N_NODES*4*4);
  ushort* pbias  = (ushort*)alloc((size_t)N_NODES*128*2);
  ushort* z      = (ushort*)alloc((size_t)N_NODES*64*2);
  ushort* q1     = (ushort*)alloc((size_t)N_NODES*64*2);
  ushort* q2     = (ushort*)alloc((size_t)N_NODES*64*2);
  ushort* q3     = (ushort*)alloc((size_t)N_NODES*64*2);
  ushort* t1     = (ushort*)alloc((size_t)N_NODES*128*2);
  ushort* p1     = (ushort*)alloc((size_t)N_NODES*128*2);
  ushort* p2     = (ushort*)alloc((size_t)N_NODES*128*2);
  ushort* p3     = (ushort*)alloc((size_t)N_NODES*128*2);
  ushort* t2     = (ushort*)alloc((size_t)N_NODES*128*2);
  ushort* PB1    = (ushort*)alloc((size_t)4*8*128*8*2);
  ushort* PB2    = (ushort*)alloc((size_t)4*16*128*8*2);
  ushort* PB3    = (ushort*)alloc((size_t)16*256*8*2);
  // fp8 shadow arrays (gather sources)
  uchar*  z8     = (uchar*)alloc((size_t)N_NODES*64);
  uchar*  q1_8   = (uchar*)alloc((size_t)N_NODES*64);
  uchar*  q2_8   = (uchar*)alloc((size_t)N_NODES*64);
  uchar*  t1_8   = (uchar*)alloc((size_t)N_NODES*128);
  uchar*  p1_8   = (uchar*)alloc((size_t)N_NODES*128);
  uchar*  p2_8   = (uchar*)alloc((size_t)N_NODES*128);
  uchar*  Y3_8   = (uchar*)alloc((size_t)N_NODES*64);
  uchar*  u1_8   = (uchar*)alloc((size_t)N_NODES*64);
  uchar*  u2_8   = (uchar*)alloc((size_t)N_NODES*64);

  // aliases: Y overlays p1+p2 (dead by gemm_y); u1,u2 (bf16, final iter) reuse q1,q2
  ushort* Y  = p1;
  ushort* Y0 = Y;
  ushort* Y1 = Y + (size_t)1*N_NODES*64;
  ushort* Y2 = Y + (size_t)2*N_NODES*64;
  ushort* Y3 = Y + (size_t)3*N_NODES*64;
  ushort* u1 = q1;
  ushort* u2 = q2;

  float* outv  = (float*)d_out;            // (N,1)
  float* zstar = (float*)d_out + N_NODES;  // (N,64)

  hipMemsetAsync(deg, 0, (size_t)N_NODES*4, stream);
  hipMemsetAsync(cnt, 0, (size_t)N_NODES*4, stream);
  int eb = (N_EDGES+255)/256;
  deg_cnt_kernel<<<eb,256,0,stream>>>(col, eattr, deg, cnt);
  norm_kernel<<<eb,256,0,stream>>>(row, col, eattr, deg, nrm);
  scan_kernel<<<1,1024,0,stream>>>(cnt, starts, cursor);
  fill_kernel<<<eb,256,0,stream>>>(row, col, nrm, cursor, crow, cnrm);
  pack_w1<<<128,256,0,stream>>>(c1_w, PB1);
  pack_w2<<<256,256,0,stream>>>(c2_w, PB2);
  pack_w3<<<128,256,0,stream>>>(c3_w, PB3);
  mlp_up_kernel<<<N_NODES/4,256,0,stream>>>(x, up_w1, up_b1, up_w2, up_b2, z, z8);

  int nb = (N_NODES+255)/256;
  posprop<3><<<nb,256,0,stream>>>(pos, P1, starts, crow, cnrm);
  posprop<4><<<nb,256,0,stream>>>(P1,  P2, starts, crow, cnrm);
  posprop<4><<<nb,256,0,stream>>>(P2,  P3, starts, crow, cnrm);
  posbias_kernel<<<(N_NODES*128)/256,256,0,stream>>>(pos, P1, P2, P3, c1_w, c1_b, pbias);

  const int gprop = N_NODES/4;             // 12500 blocks
  const int ggemm = (N_NODES+63)/64;       // 782 blocks

  for (int it=0; it<=MAX_ITER; ++it){
    if (it < MAX_ITER){
      // fp8 gather path (contraction iterations)
      prop64k<0,true,true> <<<gprop,256,0,stream>>>(z8,   q1, q1_8, nullptr, nullptr, nullptr, starts, crow, cnrm);
      prop64k<0,true,true> <<<gprop,256,0,stream>>>(q1_8, q2, q2_8, nullptr, nullptr, nullptr, starts, crow, cnrm);
      prop64k<0,true,false><<<gprop,256,0,stream>>>(q2_8, q3, nullptr, nullptr, nullptr, nullptr, starts, crow, cnrm);
      gemm4in<64,true,true><<<ggemm,256,0,stream>>>(z,q1,q2,q3,PB1,pbias,t1,t1_8);

      prop128k<true,true> <<<gprop,256,0,stream>>>(t1_8, p1, p1_8, starts, crow, cnrm);
      prop128k<true,true> <<<gprop,256,0,stream>>>(p1_8, p2, p2_8, starts, crow, cnrm);
      prop128k<true,false><<<gprop,256,0,stream>>>(p2_8, p3, nullptr, starts, crow, cnrm);
      gemm4in<128,false,false><<<ggemm,256,0,stream>>>(t1,p1,p2,p3,PB2,c2_b,t2,nullptr);

      gemm_y<<<ggemm,256,0,stream>>>(t2, PB3, Y, Y3_8);
      prop64k<1,true,true><<<gprop,256,0,stream>>>(Y3_8, nullptr, u1_8, nullptr, Y2, nullptr, starts, crow, cnrm);
      prop64k<1,true,true><<<gprop,256,0,stream>>>(u1_8, nullptr, u2_8, nullptr, Y1, nullptr, starts, crow, cnrm);
      prop64k<2,true,true><<<gprop,256,0,stream>>>(u2_8, z, z8, nullptr, Y0, c3_b, starts, crow, cnrm);
    } else {
      // final clean bf16 pass -> zstar
      prop64k<0,false,false><<<gprop,256,0,stream>>>(z,  q1, nullptr, nullptr, nullptr, nullptr, starts, crow, cnrm);
      prop64k<0,false,false><<<gprop,256,0,stream>>>(q1, q2, nullptr, nullptr, nullptr, nullptr, starts, crow, cnrm);
      prop64k<0,false,false><<<gprop,256,0,stream>>>(q2, q3, nullptr, nullptr, nullptr, nullptr, starts, crow, cnrm);
      gemm4in<64,true,false><<<ggemm,256,0,stream>>>(z,q1,q2,q3,PB1,pbias,t1,nullptr);

      prop128k<false,false><<<gprop,256,0,stream>>>(t1, p1, nullptr, starts, crow, cnrm);
      prop128k<false,false><<<gprop,256,0,stream>>>(p1, p2, nullptr, starts, crow, cnrm);
      prop128k<false,false><<<gprop,256,0,stream>>>(p2, p3, nullptr, starts, crow, cnrm);
      gemm4in<128,false,false><<<ggemm,256,0,stream>>>(t1,p1,p2,p3,PB2,c2_b,t2,nullptr);

      gemm_y<<<ggemm,256,0,stream>>>(t2, PB3, Y, Y3_8);
      prop64k<1,false,false><<<gprop,256,0,stream>>>(Y3, u1, nullptr, nullptr, Y2, nullptr, starts, crow, cnrm);
      prop64k<1,false,false><<<gprop,256,0,stream>>>(u1, u2, nullptr, nullptr, Y1, nullptr, starts, crow, cnrm);
      prop64k<3,false,false><<<gprop,256,0,stream>>>(u2, nullptr, nullptr, zstar, Y0, c3_b, starts, crow, cnrm);
    }
  }
  mlp_down_kernel<<<N_NODES/4,256,0,stream>>>(zstar, dw1, db1, dw2, db2, outv);
}